// Round 5
// baseline (459.803 us; speedup 1.0000x reference)
//
#include <hip/hip_runtime.h>

// TranslateCube: out[n, y, x] = bilinear sample of img[n] at (y - dy[n], x - dx[n]),
// zero fill outside. B*T = 1024 images, H = W = 256, fp32.
//
// v5 (resubmit; round-4 failure was container acquisition, not the kernel):
// persistent pipelined band processor (T14 issue-early / write-late).
//   Skeleton = v3 (best known): scalar weights wx=frac(-tx), wy=frac(-ty);
//   integer shift sx=a+off (a 4-aligned, off in [0,3]); LDS holds a pre-shifted
//   zero-padded 17-row x 260-col source window; per-pixel = 2 adjacent-pair LDS
//   reads + 4 FMA + 1 coalesced store (identical expression tree -> identical
//   numerics to the passing v3, absmax 0.0156).
//
//   One block owns a HALF-IMAGE (8 bands of 16 rows, same n -> all shift state
//   uniform for the block's whole life).  Software pipeline per band:
//     issue band i+1 staging loads -> regs   (5 float4/thread, independent)
//     compute band i from LDS, nontemporal stores
//     __syncthreads()                         (LDS reads of band i done)
//     ds_write regs -> LDS                    (compiler inserts counted vmcnt)
//     __syncthreads()
//   HBM read latency hides under compute; waves keep loads in flight
//   continuously instead of the stage->drain->compute->die burst pattern.
//
//   Window groups are 4-aligned, so every float4 group is fully inside or
//   fully outside [0,256) -> no per-element edge masking.
//
// Mapping: grid = (B*T)*2 blocks x 256 threads (8 blocks/CU, 17.7 KB LDS).
//   blockIdx.x >> 1 -> image n;  & 1 -> top/bottom half (8 bands).

typedef float f32x4 __attribute__((ext_vector_type(4)));

constexpr int HH = 256;
constexpr int WW = 256;
constexpr int RB = 16;            // rows per band
constexpr int SROWS = RB + 1;     // staged source rows per band
constexpr int LW  = 260;          // LDS floats per staged row (off+x+1 <= 259)
constexpr int LW4 = LW / 4;       // 65 float4 groups per row
constexpr int NSTG  = SROWS * LW4;          // 1105 float4 stage elements
constexpr int NSLOT = (NSTG + 255) / 256;   // 5 slots per thread
constexpr int BANDS = 8;          // bands per block (half image)

__global__ __launch_bounds__(256) void translate_kernel(
    const float* __restrict__ img,
    const float* __restrict__ dx,
    const float* __restrict__ dy,
    float* __restrict__ out)
{
    // +1 scratch float4 at the end: inactive slots dump there harmlessly.
    __shared__ __align__(16) float lds[SROWS * LW + 4];
    f32x4* const lds4 = (f32x4*)lds;

    const int n    = blockIdx.x >> 1;
    const int half = blockIdx.x & 1;
    const int tid  = threadIdx.x;

    const float tx = dx[n];                  // wave-uniform -> scalar
    const float ty = dy[n];
    const float fxf = floorf(-tx);
    const float fyf = floorf(-ty);
    const float wx   = (-tx) - fxf;          // in [0,1)
    const float wy   = (-ty) - fyf;
    const float omwx = 1.0f - wx;
    const float omwy = 1.0f - wy;
    const int sx = (int)fxf;
    const int sy = (int)fyf;
    const int astart = sx & ~3;              // 4-aligned first staged source col
    const int off    = sx - astart;          // 0..3, uniform

    const float* __restrict__ base = img + (size_t)n * (HH * WW);
    float* __restrict__ outb       = out + (size_t)n * (HH * WW);

    // ---- band-invariant per-slot staging descriptors ----
    int  s_rr[NSLOT];     // staged row within window
    int  s_adr[NSLOT];    // rr*WW + g  (source addr offset from band row base)
    int  s_lds[NSLOT];    // float4 index into lds (scratch slot if inactive)
    bool s_ok[NSLOT];     // active && column-group inside image
    #pragma unroll
    for (int s = 0; s < NSLOT; ++s) {
        const int e = tid + (s << 8);
        const bool act = (e < NSTG);
        const int e2 = act ? e : 0;
        const int rr = e2 / LW4;
        const int cc = e2 - rr * LW4;
        const int g  = astart + (cc << 2);   // 4-aligned: group all-in or all-out
        s_rr[s]  = rr;
        s_adr[s] = rr * WW + g;
        s_lds[s] = act ? e2 : NSTG;          // inactive -> scratch float4
        s_ok[s]  = act && ((unsigned)g < (unsigned)WW);
    }

    const int lane = tid & 63;
    const int wv   = tid >> 6;
    const int ybase = half * 128;

    f32x4 pf[NSLOT];

    // issue staging loads for band i into pf
    auto load_band = [&](int i, f32x4 (&p)[NSLOT]) {
        const int r0 = ybase + i * RB + sy;  // first source row of window
        #pragma unroll
        for (int s = 0; s < NSLOT; ++s) {
            f32x4 v = {0.f, 0.f, 0.f, 0.f};
            const int srow = r0 + s_rr[s];
            if (s_ok[s] && (unsigned)srow < (unsigned)HH)
                v = *(const f32x4*)(base + r0 * WW + s_adr[s]);
            p[s] = v;
        }
    };
    auto write_band = [&](const f32x4 (&p)[NSLOT]) {
        #pragma unroll
        for (int s = 0; s < NSLOT; ++s)
            lds4[s_lds[s]] = p[s];
    };
    auto compute_band = [&](int i) {
        const int yb = ybase + i * RB;
        #pragma unroll
        for (int jr = 0; jr < 4; ++jr) {
            const int r = (wv << 2) | jr;                 // row within band
            const float* __restrict__ L0 = &lds[r * LW + off];
            const float* __restrict__ L1 = L0 + LW;
            float* __restrict__ orow = outb + (size_t)(yb + r) * WW;
            #pragma unroll
            for (int k = 0; k < 4; ++k) {
                const int x = (k << 6) | lane;            // stride-1 across lanes
                const float c00 = L0[x];
                const float c01 = L0[x + 1];
                const float c10 = L1[x];
                const float c11 = L1[x + 1];
                const float top = omwx * c00 + wx * c01;
                const float bot = omwx * c10 + wx * c11;
                __builtin_nontemporal_store(omwy * top + wy * bot, orow + x);
            }
        }
    };

    // ---- prologue: stage band 0 ----
    load_band(0, pf);
    write_band(pf);            // compiler inserts the vmcnt before ds_write
    __syncthreads();

    // ---- pipelined main loop ----
    for (int i = 0; i < BANDS; ++i) {
        if (i + 1 < BANDS) load_band(i + 1, pf);   // issue early (T14)
        compute_band(i);                           // hides the HBM latency
        __syncthreads();                           // LDS reads of band i done
        if (i + 1 < BANDS) write_band(pf);         // write late
        __syncthreads();
    }
}

extern "C" void kernel_launch(void* const* d_in, const int* in_sizes, int n_in,
                              void* d_out, int out_size, void* d_ws, size_t ws_size,
                              hipStream_t stream) {
    const float* img = (const float*)d_in[0];  // [B,T,H,W] fp32
    const float* dx  = (const float*)d_in[1];  // [B,T]
    const float* dy  = (const float*)d_in[2];  // [B,T]
    // d_in[3] = winsize (unused)
    float* out = (float*)d_out;

    const int BT = in_sizes[1];                // number of images (B*T)
    const int nblocks = BT * 2;                // one block per half-image

    translate_kernel<<<nblocks, 256, 0, stream>>>(img, dx, dy, out);
}